// Round 9
// baseline (186.636 us; speedup 1.0000x reference)
//
#include <hip/hip_runtime.h>

#define NNODES 50000
#define NEDGES 800000
#define FDIM 128
#define HDIM 128
#define CDIM 16

#define NBUCK 256
#define BCAP 6144   // per-bucket capacity: mean 4096, sd 64 -> 32 sigma headroom
#define NBA 391     // binA blocks: ceil(800000/2048)

typedef __attribute__((ext_vector_type(8))) short bf16x8;
typedef __attribute__((ext_vector_type(4))) float f32x4;

__device__ __forceinline__ ushort f32_to_bf16_rne(float f) {
  unsigned u = __float_as_uint(f);
  unsigned rounded = u + 0x7fffu + ((u >> 16) & 1u);
  return (ushort)(rounded >> 16);
}
__device__ __forceinline__ float bf_lo(unsigned u) { return __uint_as_float(u << 16); }
__device__ __forceinline__ float bf_hi(unsigned u) { return __uint_as_float(u & 0xffff0000u); }

// ---------------- merged: binA (blocks < NBA) + prep (rest) ----------------
// binA: bucket edges by dst>>8; gcur starts 0 (memset), cursors bucket-relative.
// prep: cast x->bf16, W1T, W2T.
__global__ __launch_bounds__(256) void k_prep_binA(
    const int* __restrict__ src, const int* __restrict__ dst,
    int* __restrict__ gcur, unsigned* __restrict__ ebuf,
    const float* __restrict__ x, ushort* __restrict__ xh,
    const float* __restrict__ W1, ushort* __restrict__ W1T,
    const float* __restrict__ W2, ushort* __restrict__ W2T) {
  __shared__ int cnt[NBUCK];
  __shared__ int base[NBUCK];
  int tid = threadIdx.x;
  if (blockIdx.x < NBA) {
    int e0 = blockIdx.x * 2048;
    cnt[tid] = 0;
    __syncthreads();
    int sv[8], dv[8];
    #pragma unroll
    for (int i = 0; i < 8; ++i) {
      int e = e0 + i * 256 + tid;
      if (e < NEDGES) {
        sv[i] = src[e];
        dv[i] = dst[e];
        atomicAdd(&cnt[dv[i] >> 8], 1);
      } else {
        dv[i] = -1;
      }
    }
    __syncthreads();
    base[tid] = atomicAdd(&gcur[tid], cnt[tid]);  // bucket-relative base
    cnt[tid] = 0;  // reuse as local cursor
    __syncthreads();
    #pragma unroll
    for (int i = 0; i < 8; ++i) {
      if (dv[i] >= 0) {
        int b = dv[i] >> 8;
        int pos = base[b] + atomicAdd(&cnt[b], 1);
        if (pos < BCAP)  // safety clamp (statistically impossible)
          ebuf[b * BCAP + pos] = ((unsigned)(dv[i] & 255) << 16) | (unsigned)sv[i];
      }
    }
    return;
  }
  // ---- prep range ----
  int t = (blockIdx.x - NBA) * 256 + tid;
  if (t < 1600000) {
    float4 v = *reinterpret_cast<const float4*>(&x[t * 4]);
    ushort4 o;
    o.x = f32_to_bf16_rne(v.x);
    o.y = f32_to_bf16_rne(v.y);
    o.z = f32_to_bf16_rne(v.z);
    o.w = f32_to_bf16_rne(v.w);
    *reinterpret_cast<ushort4*>(&xh[t * 4]) = o;
    return;
  }
  t -= 1600000;
  if (t < 16384) {  // W1T[c][k] = bf16(W1[k][c])
    int c = t >> 7, k = t & 127;
    W1T[c * 128 + k] = f32_to_bf16_rne(W1[k * 128 + c]);
    return;
  }
  t -= 16384;
  if (t < 2048) {  // W2T[c][k] = bf16(W2[k][c])
    int c = t >> 7, k = t & 127;
    W2T[c * 128 + k] = f32_to_bf16_rne(W2[k * 16 + c]);
  }
}

// ---------------- phase B: per-bucket CSR finalize (all atomics in LDS) -----
__global__ __launch_bounds__(256) void k_binB(
    const int* __restrict__ gcur, const unsigned* __restrict__ ebuf,
    int* __restrict__ deg, int* __restrict__ offs, ushort* __restrict__ ssrc) {
  __shared__ int s[NBUCK];
  __shared__ int doff[NBUCK];
  __shared__ int dcur[NBUCK];
  int tid = threadIdx.x;
  int b = blockIdx.x;

  int c = gcur[tid];
  if (c > BCAP) c = BCAP;
  s[tid] = c;
  for (int off = 1; off < 256; off <<= 1) {
    __syncthreads();
    int t = (tid >= off) ? s[tid - off] : 0;
    __syncthreads();
    s[tid] += t;
  }
  __syncthreads();
  int my_base = (b > 0) ? s[b - 1] : 0;  // exclusive prefix
  int count = s[b] - my_base;

  dcur[tid] = 0;
  __syncthreads();
  const unsigned* eb = &ebuf[b * BCAP];
  for (int e = tid; e < count; e += 256) {
    atomicAdd(&dcur[eb[e] >> 16], 1);
  }
  __syncthreads();
  int dn = dcur[tid];
  s[tid] = dn;
  for (int off = 1; off < 256; off <<= 1) {
    __syncthreads();
    int t = (tid >= off) ? s[tid - off] : 0;
    __syncthreads();
    s[tid] += t;
  }
  __syncthreads();
  doff[tid] = s[tid] - dn;  // exclusive within bucket
  int node = b * 256 + tid;
  if (node < NNODES) {
    deg[node] = dn;
    offs[node] = my_base + doff[tid];
  }
  dcur[tid] = 0;
  __syncthreads();

  for (int e = tid; e < count; e += 256) {
    unsigned v = eb[e];
    int loc = v >> 16;
    int pos = my_base + doff[loc] + atomicAdd(&dcur[loc], 1);
    ssrc[pos] = (ushort)(v & 0xffffu);
  }
}

// ------- fused spmm1 + dense: z = (relu(mean(x)@W1+b1)*mask) @ W2 ----------
// block = 256 thr = 4 waves, 64 nodes. Phase 1: gather-mean x (bf16) into LDS
// agg tile. Phase 2: per-wave MFMA chain (16 nodes) off LDS A-frags.
// A-frag: lane holds A[m=lane&15][k=quad*8+j]; C/D: col=lane&15, row=quad*4+reg.
#define AG_STRIDE 136  // shorts (272B rows): +8B skew per row, <=2-way bank alias
#define HT_STRIDE 132
__global__ __launch_bounds__(256) void k_spmm_dense(
    const ushort* __restrict__ xh, const int* __restrict__ offs,
    const int* __restrict__ deg, const ushort* __restrict__ ssrc,
    const ushort* __restrict__ W1T, const float* __restrict__ b1,
    const float* __restrict__ mask, const ushort* __restrict__ W2T,
    ushort* __restrict__ zh) {
  __shared__ ushort sAgg[64 * AG_STRIDE];
  __shared__ ushort hT[4][16 * HT_STRIDE];
  int tid = threadIdx.x;
  int nb = blockIdx.x * 64;

  // ---- phase 1: gather-mean; node-group = 16 lanes, 4 nodes sequential ----
  int grp = tid >> 4;   // 0..15
  int l16 = tid & 15;   // channel group: ch [8*l16, 8*l16+8)
  const ushort* gbase = xh + l16 * 8;
  for (int i = 0; i < 4; ++i) {
    int nl = grp * 4 + i;
    int n = nb + nl;
    uint4 o = make_uint4(0, 0, 0, 0);
    if (n < NNODES) {
      int start = offs[n];
      int d = deg[n];
      float a0[8] = {0,0,0,0,0,0,0,0};
      float a1[8] = {0,0,0,0,0,0,0,0};
      float a2[8] = {0,0,0,0,0,0,0,0};
      float a3[8] = {0,0,0,0,0,0,0,0};
      int j = 0;
      for (; j + 3 < d; j += 4) {
        int s0 = ssrc[start + j + 0];
        int s1 = ssrc[start + j + 1];
        int s2 = ssrc[start + j + 2];
        int s3 = ssrc[start + j + 3];
        uint4 u0 = *reinterpret_cast<const uint4*>(gbase + s0 * FDIM);
        uint4 u1 = *reinterpret_cast<const uint4*>(gbase + s1 * FDIM);
        uint4 u2 = *reinterpret_cast<const uint4*>(gbase + s2 * FDIM);
        uint4 u3 = *reinterpret_cast<const uint4*>(gbase + s3 * FDIM);
        a0[0] += bf_lo(u0.x); a0[1] += bf_hi(u0.x); a0[2] += bf_lo(u0.y); a0[3] += bf_hi(u0.y);
        a0[4] += bf_lo(u0.z); a0[5] += bf_hi(u0.z); a0[6] += bf_lo(u0.w); a0[7] += bf_hi(u0.w);
        a1[0] += bf_lo(u1.x); a1[1] += bf_hi(u1.x); a1[2] += bf_lo(u1.y); a1[3] += bf_hi(u1.y);
        a1[4] += bf_lo(u1.z); a1[5] += bf_hi(u1.z); a1[6] += bf_lo(u1.w); a1[7] += bf_hi(u1.w);
        a2[0] += bf_lo(u2.x); a2[1] += bf_hi(u2.x); a2[2] += bf_lo(u2.y); a2[3] += bf_hi(u2.y);
        a2[4] += bf_lo(u2.z); a2[5] += bf_hi(u2.z); a2[6] += bf_lo(u2.w); a2[7] += bf_hi(u2.w);
        a3[0] += bf_lo(u3.x); a3[1] += bf_hi(u3.x); a3[2] += bf_lo(u3.y); a3[3] += bf_hi(u3.y);
        a3[4] += bf_lo(u3.z); a3[5] += bf_hi(u3.z); a3[6] += bf_lo(u3.w); a3[7] += bf_hi(u3.w);
      }
      for (; j < d; ++j) {
        int s0 = ssrc[start + j];
        uint4 u0 = *reinterpret_cast<const uint4*>(gbase + s0 * FDIM);
        a0[0] += bf_lo(u0.x); a0[1] += bf_hi(u0.x); a0[2] += bf_lo(u0.y); a0[3] += bf_hi(u0.y);
        a0[4] += bf_lo(u0.z); a0[5] += bf_hi(u0.z); a0[6] += bf_lo(u0.w); a0[7] += bf_hi(u0.w);
      }
      float inv = 1.0f / (float)(d > 0 ? d : 1);
      unsigned r[4];
      #pragma unroll
      for (int k = 0; k < 4; ++k) {
        float e0 = (a0[2 * k] + a1[2 * k] + a2[2 * k] + a3[2 * k]) * inv;
        float e1 = (a0[2 * k + 1] + a1[2 * k + 1] + a2[2 * k + 1] + a3[2 * k + 1]) * inv;
        r[k] = (unsigned)f32_to_bf16_rne(e0) | ((unsigned)f32_to_bf16_rne(e1) << 16);
      }
      o.x = r[0]; o.y = r[1]; o.z = r[2]; o.w = r[3];
    }
    *reinterpret_cast<uint4*>(&sAgg[nl * AG_STRIDE + l16 * 8]) = o;
  }
  __syncthreads();

  // ---- phase 2: MFMA chain per wave (16 nodes) ----
  int w = tid >> 6;
  int lane = tid & 63;
  int l15 = lane & 15, quad = lane >> 4;
  int nw = nb + w * 16;

  f32x4 acc[8];
  #pragma unroll
  for (int ct = 0; ct < 8; ++ct) acc[ct] = (f32x4){0.f, 0.f, 0.f, 0.f};

  const ushort* arow = &sAgg[(w * 16 + l15) * AG_STRIDE + quad * 8];
  #pragma unroll
  for (int kk = 0; kk < 4; ++kk) {
    bf16x8 a = *reinterpret_cast<const bf16x8*>(arow + kk * 32);
    #pragma unroll
    for (int ct = 0; ct < 8; ++ct) {
      bf16x8 b = *reinterpret_cast<const bf16x8*>(
          &W1T[(size_t)(ct * 16 + l15) * 128 + kk * 32 + quad * 8]);
      acc[ct] = __builtin_amdgcn_mfma_f32_16x16x32_bf16(a, b, acc[ct], 0, 0, 0);
    }
  }

  // epilogue: +b1, relu, *mask -> bf16 LDS tile [row=node_local][col]
  ushort* ht = hT[w];
  #pragma unroll
  for (int ct = 0; ct < 8; ++ct) {
    int col = ct * 16 + l15;
    float bb = b1[col];
    #pragma unroll
    for (int r = 0; r < 4; ++r) {
      int node = nw + quad * 4 + r;
      float v = 0.f;
      if (node < NNODES) {
        v = acc[ct][r] + bb;
        v = v > 0.f ? v : 0.f;
        v *= mask[(size_t)node * 128 + col];
      }
      ht[(quad * 4 + r) * HT_STRIDE + col] = f32_to_bf16_rne(v);
    }
  }
  // wave-private tile: compiler inserts lgkmcnt before dependent reads

  // second GEMM: z_tile[16n x 16c] = hT @ W2 (4 x K=32 MFMA steps)
  f32x4 zacc = (f32x4){0.f, 0.f, 0.f, 0.f};
  #pragma unroll
  for (int kk = 0; kk < 4; ++kk) {
    const ushort* ap = &ht[l15 * HT_STRIDE + kk * 32 + quad * 8];
    ushort4 alo = *reinterpret_cast<const ushort4*>(ap);
    ushort4 ahi = *reinterpret_cast<const ushort4*>(ap + 4);
    bf16x8 a2 = (bf16x8){(short)alo.x, (short)alo.y, (short)alo.z, (short)alo.w,
                         (short)ahi.x, (short)ahi.y, (short)ahi.z, (short)ahi.w};
    bf16x8 b2 = *reinterpret_cast<const bf16x8*>(&W2T[l15 * 128 + kk * 32 + quad * 8]);
    zacc = __builtin_amdgcn_mfma_f32_16x16x32_bf16(a2, b2, zacc, 0, 0, 0);
  }
  #pragma unroll
  for (int r = 0; r < 4; ++r) {
    int node = nw + quad * 4 + r;
    if (node < NNODES)
      zh[(size_t)node * 16 + l15] = f32_to_bf16_rne(zacc[r]);
  }
}

// ---------------- layer 2 aggregate + bias: out = mean(z) + b2 ----------------
__global__ void k_spmm2(const ushort* __restrict__ zh, const int* __restrict__ offs,
                        const int* __restrict__ deg, const ushort* __restrict__ ssrc,
                        const float* __restrict__ b2, float* __restrict__ out) {
  int tid = threadIdx.x;
  int nl = tid >> 4, c = tid & 15;
  int n = blockIdx.x * 8 + nl;
  if (n >= NNODES) return;
  int start = offs[n], d = deg[n];
  float a0 = 0.f, a1 = 0.f, a2 = 0.f, a3 = 0.f;
  int j = 0;
  for (; j + 3 < d; j += 4) {
    int s0 = ssrc[start + j + 0], s1 = ssrc[start + j + 1];
    int s2 = ssrc[start + j + 2], s3 = ssrc[start + j + 3];
    a0 += __uint_as_float((unsigned)zh[s0 * 16 + c] << 16);
    a1 += __uint_as_float((unsigned)zh[s1 * 16 + c] << 16);
    a2 += __uint_as_float((unsigned)zh[s2 * 16 + c] << 16);
    a3 += __uint_as_float((unsigned)zh[s3 * 16 + c] << 16);
  }
  for (; j < d; ++j) a0 += __uint_as_float((unsigned)zh[ssrc[start + j] * 16 + c] << 16);
  out[n * 16 + c] = (a0 + a1 + a2 + a3) / (float)(d > 0 ? d : 1) + b2[c];
}

// ---------------- launch ----------------

extern "C" void kernel_launch(void* const* d_in, const int* in_sizes, int n_in,
                              void* d_out, int out_size, void* d_ws, size_t ws_size,
                              hipStream_t stream) {
  const float* x    = (const float*)d_in[0];
  const int*   ei   = (const int*)d_in[1];
  const float* W1   = (const float*)d_in[2];
  const float* b1   = (const float*)d_in[3];
  const float* W2   = (const float*)d_in[4];
  const float* b2   = (const float*)d_in[5];
  const float* mask = (const float*)d_in[6];
  float* out = (float*)d_out;

  const int* src = ei;            // edge_index[0]
  const int* dst = ei + NEDGES;   // edge_index[1]

  char* ws = (char*)d_ws;
  size_t o = 0;
  auto alloc = [&](size_t bytes) -> void* {
    void* p = ws + o;
    o += (bytes + 255) & ~(size_t)255;
    return p;
  };
  ushort*   xh   = (ushort*)alloc((size_t)NNODES * 128 * 2);
  ushort*   zh   = (ushort*)alloc((size_t)NNODES * 16 * 2);
  ushort*   W1T  = (ushort*)alloc((size_t)128 * 128 * 2);
  ushort*   W2T  = (ushort*)alloc((size_t)16 * 128 * 2);
  int*      deg  = (int*)alloc((size_t)NNODES * 4);
  int*      offs = (int*)alloc((size_t)NNODES * 4);
  int*      gcur = (int*)alloc((size_t)NBUCK * 4);
  unsigned* ebuf = (unsigned*)alloc((size_t)NBUCK * BCAP * 4);
  ushort*   ssrc = (ushort*)alloc((size_t)NEDGES * 2);

  int prep_threads = 1600000 + 16384 + 2048;
  int prep_blocks = (prep_threads + 255) / 256;

  hipMemsetAsync(gcur, 0, NBUCK * sizeof(int), stream);
  k_prep_binA<<<NBA + prep_blocks, 256, 0, stream>>>(src, dst, gcur, ebuf,
                                                     x, xh, W1, W1T, W2, W2T);
  k_binB<<<NBUCK, 256, 0, stream>>>(gcur, ebuf, deg, offs, ssrc);
  k_spmm_dense<<<(NNODES + 63) / 64, 256, 0, stream>>>(xh, offs, deg, ssrc,
                                                       W1T, b1, mask, W2T, zh);
  k_spmm2<<<(NNODES + 7) / 8, 128, 0, stream>>>(zh, offs, deg, ssrc, b2, out);
}

// Round 10
// 181.537 us; speedup vs baseline: 1.0281x; 1.0281x over previous
//
#include <hip/hip_runtime.h>

#define NNODES 50000
#define NEDGES 800000
#define FDIM 128
#define HDIM 128
#define CDIM 16

#define NBUCK 256
#define BCAP 6144   // per-bucket capacity: mean 4096, sd 64 -> 32 sigma headroom
#define NBA 391     // binA blocks: ceil(800000/2048)

typedef __attribute__((ext_vector_type(8))) short bf16x8;
typedef __attribute__((ext_vector_type(4))) float f32x4;

__device__ __forceinline__ ushort f32_to_bf16_rne(float f) {
  unsigned u = __float_as_uint(f);
  unsigned rounded = u + 0x7fffu + ((u >> 16) & 1u);
  return (ushort)(rounded >> 16);
}
__device__ __forceinline__ float bf_lo(unsigned u) { return __uint_as_float(u << 16); }
__device__ __forceinline__ float bf_hi(unsigned u) { return __uint_as_float(u & 0xffff0000u); }

// ---------------- merged: binA (blocks < NBA) + prep (rest) ----------------
__global__ __launch_bounds__(256) void k_prep_binA(
    const int* __restrict__ src, const int* __restrict__ dst,
    int* __restrict__ gcur, unsigned* __restrict__ ebuf,
    const float* __restrict__ x, ushort* __restrict__ xh,
    const float* __restrict__ W1, ushort* __restrict__ W1T,
    const float* __restrict__ W2, ushort* __restrict__ W2T) {
  __shared__ int cnt[NBUCK];
  __shared__ int base[NBUCK];
  int tid = threadIdx.x;
  if (blockIdx.x < NBA) {
    int e0 = blockIdx.x * 2048;
    cnt[tid] = 0;
    __syncthreads();
    int sv[8], dv[8];
    #pragma unroll
    for (int i = 0; i < 8; ++i) {
      int e = e0 + i * 256 + tid;
      if (e < NEDGES) {
        sv[i] = src[e];
        dv[i] = dst[e];
        atomicAdd(&cnt[dv[i] >> 8], 1);
      } else {
        dv[i] = -1;
      }
    }
    __syncthreads();
    base[tid] = atomicAdd(&gcur[tid], cnt[tid]);  // bucket-relative base
    cnt[tid] = 0;  // reuse as local cursor
    __syncthreads();
    #pragma unroll
    for (int i = 0; i < 8; ++i) {
      if (dv[i] >= 0) {
        int b = dv[i] >> 8;
        int pos = base[b] + atomicAdd(&cnt[b], 1);
        if (pos < BCAP)  // safety clamp (statistically impossible)
          ebuf[b * BCAP + pos] = ((unsigned)(dv[i] & 255) << 16) | (unsigned)sv[i];
      }
    }
    return;
  }
  // ---- prep range ----
  int t = (blockIdx.x - NBA) * 256 + tid;
  if (t < 1600000) {
    float4 v = *reinterpret_cast<const float4*>(&x[t * 4]);
    ushort4 o;
    o.x = f32_to_bf16_rne(v.x);
    o.y = f32_to_bf16_rne(v.y);
    o.z = f32_to_bf16_rne(v.z);
    o.w = f32_to_bf16_rne(v.w);
    *reinterpret_cast<ushort4*>(&xh[t * 4]) = o;
    return;
  }
  t -= 1600000;
  if (t < 16384) {  // W1T[c][k] = bf16(W1[k][c])
    int c = t >> 7, k = t & 127;
    W1T[c * 128 + k] = f32_to_bf16_rne(W1[k * 128 + c]);
    return;
  }
  t -= 16384;
  if (t < 2048) {  // W2T[c][k] = bf16(W2[k][c])
    int c = t >> 7, k = t & 127;
    W2T[c * 128 + k] = f32_to_bf16_rne(W2[k * 16 + c]);
  }
}

// ---------------- phase B: per-bucket CSR finalize (all atomics in LDS) -----
__global__ __launch_bounds__(256) void k_binB(
    const int* __restrict__ gcur, const unsigned* __restrict__ ebuf,
    int* __restrict__ deg, int* __restrict__ offs, ushort* __restrict__ ssrc) {
  __shared__ int s[NBUCK];
  __shared__ int doff[NBUCK];
  __shared__ int dcur[NBUCK];
  int tid = threadIdx.x;
  int b = blockIdx.x;

  int c = gcur[tid];
  if (c > BCAP) c = BCAP;
  s[tid] = c;
  for (int off = 1; off < 256; off <<= 1) {
    __syncthreads();
    int t = (tid >= off) ? s[tid - off] : 0;
    __syncthreads();
    s[tid] += t;
  }
  __syncthreads();
  int my_base = (b > 0) ? s[b - 1] : 0;  // exclusive prefix
  int count = s[b] - my_base;

  dcur[tid] = 0;
  __syncthreads();
  const unsigned* eb = &ebuf[b * BCAP];
  for (int e = tid; e < count; e += 256) {
    atomicAdd(&dcur[eb[e] >> 16], 1);
  }
  __syncthreads();
  int dn = dcur[tid];
  s[tid] = dn;
  for (int off = 1; off < 256; off <<= 1) {
    __syncthreads();
    int t = (tid >= off) ? s[tid - off] : 0;
    __syncthreads();
    s[tid] += t;
  }
  __syncthreads();
  doff[tid] = s[tid] - dn;  // exclusive within bucket
  int node = b * 256 + tid;
  if (node < NNODES) {
    deg[node] = dn;
    offs[node] = my_base + doff[tid];
  }
  dcur[tid] = 0;
  __syncthreads();

  for (int e = tid; e < count; e += 256) {
    unsigned v = eb[e];
    int loc = v >> 16;
    int pos = my_base + doff[loc] + atomicAdd(&dcur[loc], 1);
    ssrc[pos] = (ushort)(v & 0xffffu);
  }
}

// ---------------- layer 1: mean-aggregate bf16 x -> bf16 agg ----------------
// 16 node-groups per block; node-group = 16 lanes, lane owns 8 channels (uint4
// = 16B load -> one 1KiB coalesced fetch per wave per instr). 4 edge streams.
// Zero LDS, 3125 blocks: max gather waves in flight (fabric-BW-bound).
__global__ __launch_bounds__(256) void k_spmm1(
    const ushort* __restrict__ xh, const int* __restrict__ offs,
    const int* __restrict__ deg, const ushort* __restrict__ ssrc,
    ushort* __restrict__ aggh) {
  int tid = threadIdx.x;
  int grp = tid >> 4;   // node within block (0..15)
  int l16 = tid & 15;   // channel group: ch [8*l16, 8*l16+8)
  int n = blockIdx.x * 16 + grp;
  if (n >= NNODES) return;
  int start = offs[n];
  int d = deg[n];
  const ushort* base = xh + l16 * 8;
  float a0[8] = {0,0,0,0,0,0,0,0};
  float a1[8] = {0,0,0,0,0,0,0,0};
  float a2[8] = {0,0,0,0,0,0,0,0};
  float a3[8] = {0,0,0,0,0,0,0,0};
  int j = 0;
  for (; j + 3 < d; j += 4) {
    int s0 = ssrc[start + j + 0];
    int s1 = ssrc[start + j + 1];
    int s2 = ssrc[start + j + 2];
    int s3 = ssrc[start + j + 3];
    uint4 u0 = *reinterpret_cast<const uint4*>(base + s0 * FDIM);
    uint4 u1 = *reinterpret_cast<const uint4*>(base + s1 * FDIM);
    uint4 u2 = *reinterpret_cast<const uint4*>(base + s2 * FDIM);
    uint4 u3 = *reinterpret_cast<const uint4*>(base + s3 * FDIM);
    a0[0] += bf_lo(u0.x); a0[1] += bf_hi(u0.x); a0[2] += bf_lo(u0.y); a0[3] += bf_hi(u0.y);
    a0[4] += bf_lo(u0.z); a0[5] += bf_hi(u0.z); a0[6] += bf_lo(u0.w); a0[7] += bf_hi(u0.w);
    a1[0] += bf_lo(u1.x); a1[1] += bf_hi(u1.x); a1[2] += bf_lo(u1.y); a1[3] += bf_hi(u1.y);
    a1[4] += bf_lo(u1.z); a1[5] += bf_hi(u1.z); a1[6] += bf_lo(u1.w); a1[7] += bf_hi(u1.w);
    a2[0] += bf_lo(u2.x); a2[1] += bf_hi(u2.x); a2[2] += bf_lo(u2.y); a2[3] += bf_hi(u2.y);
    a2[4] += bf_lo(u2.z); a2[5] += bf_hi(u2.z); a2[6] += bf_lo(u2.w); a2[7] += bf_hi(u2.w);
    a3[0] += bf_lo(u3.x); a3[1] += bf_hi(u3.x); a3[2] += bf_lo(u3.y); a3[3] += bf_hi(u3.y);
    a3[4] += bf_lo(u3.z); a3[5] += bf_hi(u3.z); a3[6] += bf_lo(u3.w); a3[7] += bf_hi(u3.w);
  }
  for (; j < d; ++j) {
    int s0 = ssrc[start + j];
    uint4 u0 = *reinterpret_cast<const uint4*>(base + s0 * FDIM);
    a0[0] += bf_lo(u0.x); a0[1] += bf_hi(u0.x); a0[2] += bf_lo(u0.y); a0[3] += bf_hi(u0.y);
    a0[4] += bf_lo(u0.z); a0[5] += bf_hi(u0.z); a0[6] += bf_lo(u0.w); a0[7] += bf_hi(u0.w);
  }
  float inv = 1.0f / (float)(d > 0 ? d : 1);
  unsigned r[4];
  #pragma unroll
  for (int k = 0; k < 4; ++k) {
    float e0 = (a0[2 * k] + a1[2 * k] + a2[2 * k] + a3[2 * k]) * inv;
    float e1 = (a0[2 * k + 1] + a1[2 * k + 1] + a2[2 * k + 1] + a3[2 * k + 1]) * inv;
    r[k] = (unsigned)f32_to_bf16_rne(e0) | ((unsigned)f32_to_bf16_rne(e1) << 16);
  }
  uint4 o; o.x = r[0]; o.y = r[1]; o.z = r[2]; o.w = r[3];
  *reinterpret_cast<uint4*>(&aggh[(size_t)n * FDIM + l16 * 8]) = o;
}

// ---------------- fused dense: z = (relu(agg@W1+b1)*mask) @ W2 ----------------
// 256 thr = 4 waves; wave = 16 nodes; h-tile lives only in LDS (bf16).
// A-frag: lane holds A[m=lane&15][k=quad*8+j]; C/D: col=lane&15, row=quad*4+reg.
#define HT_STRIDE 132  // shorts; ds b16/b64 accesses are 2-way aliased (free)
__global__ __launch_bounds__(256) void k_dense(
    const ushort* __restrict__ aggh, const ushort* __restrict__ W1T,
    const float* __restrict__ b1, const float* __restrict__ mask,
    const ushort* __restrict__ W2T, ushort* __restrict__ zh) {
  __shared__ ushort hT[4][16 * HT_STRIDE];
  int w = threadIdx.x >> 6;
  int lane = threadIdx.x & 63;
  int nw = blockIdx.x * 64 + w * 16;
  if (nw >= NNODES) return;  // whole-wave tail (NNODES % 16 == 0)
  int l15 = lane & 15, quad = lane >> 4;

  f32x4 acc[8];
  #pragma unroll
  for (int ct = 0; ct < 8; ++ct) acc[ct] = (f32x4){0.f, 0.f, 0.f, 0.f};

  const ushort* arow = &aggh[(size_t)(nw + l15) * 128 + quad * 8];
  #pragma unroll
  for (int kk = 0; kk < 4; ++kk) {
    bf16x8 a = *reinterpret_cast<const bf16x8*>(arow + kk * 32);
    #pragma unroll
    for (int ct = 0; ct < 8; ++ct) {
      bf16x8 b = *reinterpret_cast<const bf16x8*>(
          &W1T[(size_t)(ct * 16 + l15) * 128 + kk * 32 + quad * 8]);
      acc[ct] = __builtin_amdgcn_mfma_f32_16x16x32_bf16(a, b, acc[ct], 0, 0, 0);
    }
  }

  // epilogue: +b1, relu, *mask -> bf16 LDS tile [row=node_local][col]
  ushort* ht = hT[w];
  #pragma unroll
  for (int ct = 0; ct < 8; ++ct) {
    int col = ct * 16 + l15;
    float bb = b1[col];
    #pragma unroll
    for (int r = 0; r < 4; ++r) {
      int node = nw + quad * 4 + r;
      float v = acc[ct][r] + bb;
      v = v > 0.f ? v : 0.f;
      v *= mask[(size_t)node * 128 + col];
      ht[(quad * 4 + r) * HT_STRIDE + col] = f32_to_bf16_rne(v);
    }
  }
  // wave-private tile: compiler inserts lgkmcnt before dependent reads

  // second GEMM: z_tile[16n x 16c] = hT @ W2 (4 x K=32 MFMA steps)
  f32x4 zacc = (f32x4){0.f, 0.f, 0.f, 0.f};
  #pragma unroll
  for (int kk = 0; kk < 4; ++kk) {
    const ushort* ap = &ht[l15 * HT_STRIDE + kk * 32 + quad * 8];
    ushort4 alo = *reinterpret_cast<const ushort4*>(ap);
    ushort4 ahi = *reinterpret_cast<const ushort4*>(ap + 4);
    bf16x8 a2 = (bf16x8){(short)alo.x, (short)alo.y, (short)alo.z, (short)alo.w,
                         (short)ahi.x, (short)ahi.y, (short)ahi.z, (short)ahi.w};
    bf16x8 b2 = *reinterpret_cast<const bf16x8*>(&W2T[l15 * 128 + kk * 32 + quad * 8]);
    zacc = __builtin_amdgcn_mfma_f32_16x16x32_bf16(a2, b2, zacc, 0, 0, 0);
  }
  #pragma unroll
  for (int r = 0; r < 4; ++r) {
    zh[(size_t)(nw + quad * 4 + r) * 16 + l15] = f32_to_bf16_rne(zacc[r]);
  }
}

// ---------------- layer 2 aggregate + bias: out = mean(z) + b2 ----------------
__global__ void k_spmm2(const ushort* __restrict__ zh, const int* __restrict__ offs,
                        const int* __restrict__ deg, const ushort* __restrict__ ssrc,
                        const float* __restrict__ b2, float* __restrict__ out) {
  int tid = threadIdx.x;
  int nl = tid >> 4, c = tid & 15;
  int n = blockIdx.x * 8 + nl;
  if (n >= NNODES) return;
  int start = offs[n], d = deg[n];
  float a0 = 0.f, a1 = 0.f, a2 = 0.f, a3 = 0.f;
  int j = 0;
  for (; j + 3 < d; j += 4) {
    int s0 = ssrc[start + j + 0], s1 = ssrc[start + j + 1];
    int s2 = ssrc[start + j + 2], s3 = ssrc[start + j + 3];
    a0 += __uint_as_float((unsigned)zh[s0 * 16 + c] << 16);
    a1 += __uint_as_float((unsigned)zh[s1 * 16 + c] << 16);
    a2 += __uint_as_float((unsigned)zh[s2 * 16 + c] << 16);
    a3 += __uint_as_float((unsigned)zh[s3 * 16 + c] << 16);
  }
  for (; j < d; ++j) a0 += __uint_as_float((unsigned)zh[ssrc[start + j] * 16 + c] << 16);
  out[n * 16 + c] = (a0 + a1 + a2 + a3) / (float)(d > 0 ? d : 1) + b2[c];
}

// ---------------- launch ----------------

extern "C" void kernel_launch(void* const* d_in, const int* in_sizes, int n_in,
                              void* d_out, int out_size, void* d_ws, size_t ws_size,
                              hipStream_t stream) {
  const float* x    = (const float*)d_in[0];
  const int*   ei   = (const int*)d_in[1];
  const float* W1   = (const float*)d_in[2];
  const float* b1   = (const float*)d_in[3];
  const float* W2   = (const float*)d_in[4];
  const float* b2   = (const float*)d_in[5];
  const float* mask = (const float*)d_in[6];
  float* out = (float*)d_out;

  const int* src = ei;            // edge_index[0]
  const int* dst = ei + NEDGES;   // edge_index[1]

  char* ws = (char*)d_ws;
  size_t o = 0;
  auto alloc = [&](size_t bytes) -> void* {
    void* p = ws + o;
    o += (bytes + 255) & ~(size_t)255;
    return p;
  };
  ushort*   aggh = (ushort*)alloc((size_t)NNODES * 128 * 2);
  ushort*   xh   = (ushort*)alloc((size_t)NNODES * 128 * 2);
  ushort*   zh   = (ushort*)alloc((size_t)NNODES * 16 * 2);
  ushort*   W1T  = (ushort*)alloc((size_t)128 * 128 * 2);
  ushort*   W2T  = (ushort*)alloc((size_t)16 * 128 * 2);
  int*      deg  = (int*)alloc((size_t)NNODES * 4);
  int*      offs = (int*)alloc((size_t)NNODES * 4);
  int*      gcur = (int*)alloc((size_t)NBUCK * 4);
  unsigned* ebuf = (unsigned*)alloc((size_t)NBUCK * BCAP * 4);
  ushort*   ssrc = (ushort*)alloc((size_t)NEDGES * 2);

  int prep_threads = 1600000 + 16384 + 2048;
  int prep_blocks = (prep_threads + 255) / 256;

  hipMemsetAsync(gcur, 0, NBUCK * sizeof(int), stream);
  k_prep_binA<<<NBA + prep_blocks, 256, 0, stream>>>(src, dst, gcur, ebuf,
                                                     x, xh, W1, W1T, W2, W2T);
  k_binB<<<NBUCK, 256, 0, stream>>>(gcur, ebuf, deg, offs, ssrc);
  k_spmm1<<<(NNODES + 15) / 16, 256, 0, stream>>>(xh, offs, deg, ssrc, aggh);
  k_dense<<<(NNODES + 63) / 64, 256, 0, stream>>>(aggh, W1T, b1, mask, W2T, zh);
  k_spmm2<<<(NNODES + 7) / 8, 128, 0, stream>>>(zh, offs, deg, ssrc, b2, out);
}